// Round 4
// baseline (639.929 us; speedup 1.0000x reference)
//
#include <hip/hip_runtime.h>
#include <hip/hip_bf16.h>
#include <math.h>

// GNO collapsed: h = lift(x); per layer h = gelu(h@weff + beff) where
//   weff = Wb + c0*Wq@M, beff = bb + c0*bq@M,
//   M = Wk^T G Wv + (Wk^T s) bv + bk (s^T Wv) + N bk bv,  G = h^T h, s = h^T 1.
// Round-4 structure: per layer a 32-block "setup" computes weff/beff once
// (column-stripe parallel), then a 512-block lean "apply" does the O(N d^2)
// row work + G/s accumulation. Single dispatch chain with runtime dtype branch.

#define NLAYER 4
#define NB 2
#define NN 4096
#define DD 64
#define RPB 16
#define NT 256
#define NGRID ((NB*NN)/RPB)   // 512 blocks
#define C0F (1.0f/32768.0f)   // (1/sqrt(64))/4096
#define SHP 68                // padded LDS stride: 16B-aligned, worst 2-way bank alias

typedef __hip_bfloat16 bf16;

__device__ __forceinline__ float b2f(const bf16 v) { return __bfloat162float(v); }

template <typename T> struct Acc;
template <> struct Acc<float> {
    static __device__ __forceinline__ float ld(const void* p, int i) { return ((const float*)p)[i]; }
    static __device__ __forceinline__ void st(void* p, int i, float v) { ((float*)p)[i] = v; }
};
template <> struct Acc<bf16> {
    static __device__ __forceinline__ float ld(const void* p, int i) { return b2f(((const bf16*)p)[i]); }
    static __device__ __forceinline__ void st(void* p, int i, float v) { ((bf16*)p)[i] = __float2bfloat16(v); }
};

__device__ __forceinline__ float gelu_exact(float x) {
    return 0.5f * x * (1.0f + erff(x * 0.70710678118654752f));
}

// G += sH^T sH (4x4 tile/thread over RPB rows), s += column sums. Atomics.
__device__ __forceinline__ void accG(const float (*sH)[SHP], int t,
                                     float* __restrict__ Gp, float* __restrict__ sp)
{
    const int tr4 = (t >> 4) << 2, tc4 = (t & 15) << 2;
    float m[4][4];
    #pragma unroll
    for (int a = 0; a < 4; a++)
        #pragma unroll
        for (int b = 0; b < 4; b++) m[a][b] = 0.f;
    #pragma unroll
    for (int n = 0; n < RPB; n++) {
        float4 he = *(const float4*)&sH[n][tr4];
        float4 hc = *(const float4*)&sH[n][tc4];
        float ha[4] = {he.x, he.y, he.z, he.w};
        float ca[4] = {hc.x, hc.y, hc.z, hc.w};
        #pragma unroll
        for (int a = 0; a < 4; a++)
            #pragma unroll
            for (int b = 0; b < 4; b++) m[a][b] += ha[a] * ca[b];
    }
    #pragma unroll
    for (int a = 0; a < 4; a++)
        #pragma unroll
        for (int b = 0; b < 4; b++)
            atomicAdd(&Gp[(tr4 + a) * DD + tc4 + b], m[a][b]);
    if (t < DD) {
        float ss = 0.f;
        #pragma unroll
        for (int n = 0; n < RPB; n++) ss += sH[n][t];
        atomicAdd(&sp[t], ss);
    }
}

// ---- init: zero G/s, classify input dtype (1 = bf16, 0 = fp32) ----
__global__ __launch_bounds__(NT) void init_kernel(const unsigned int* __restrict__ x,
                                                  float* __restrict__ G, float* __restrict__ s,
                                                  int* __restrict__ flag)
{
    __shared__ int tot;
    const int t = threadIdx.x;
    if (t == 0) tot = 0;
    __syncthreads();
    for (int i = t; i < NLAYER * NB * DD * DD; i += NT) G[i] = 0.f;
    for (int i = t; i < NLAYER * NB * DD; i += NT) s[i] = 0.f;
    int cnt = 0;
    for (int i = t; i < 8192; i += NT) {
        unsigned u = x[i] & 0xFFFFu;
        int e = (u >> 7) & 0xFF;
        cnt += (u == 0u || (e >= 100 && e <= 142)) ? 1 : 0;
    }
    atomicAdd(&tot, cnt);
    __syncthreads();
    if (t == 0) flag[0] = (tot > 4915) ? 1 : 0;
}

// ---- lift: h = x @ lw + lb, accumulate G0/s0 ----
template <typename T>
__device__ __forceinline__ void lift_body(const void* x, const void* lw, const void* lb,
                                          float* h, float* G0, float* s0,
                                          float (*sH)[SHP], int t, int row0, int bb)
{
    const int row = t >> 4, c4 = (t & 15) << 2;
    const int gr = row0 + row;
    float x0 = Acc<T>::ld(x, gr * 3 + 0);
    float x1 = Acc<T>::ld(x, gr * 3 + 1);
    float x2 = Acc<T>::ld(x, gr * 3 + 2);
    float o[4];
    #pragma unroll
    for (int b = 0; b < 4; b++) {
        int c = c4 + b;
        o[b] = Acc<T>::ld(lb, c) + x0 * Acc<T>::ld(lw, c)
             + x1 * Acc<T>::ld(lw, DD + c) + x2 * Acc<T>::ld(lw, 2 * DD + c);
    }
    float4 o4 = make_float4(o[0], o[1], o[2], o[3]);
    *(float4*)&sH[row][c4] = o4;
    *(float4*)(h + (size_t)gr * DD + c4) = o4;
    __syncthreads();
    accG(sH, t, G0 + bb * DD * DD, s0 + bb * DD);
}

__global__ __launch_bounds__(NT, 4) void lift_kernel(const int* __restrict__ flag,
    const void* __restrict__ x, const void* __restrict__ lw, const void* __restrict__ lb,
    float* __restrict__ h, float* __restrict__ G0, float* __restrict__ s0)
{
    __shared__ float sH[RPB][SHP];
    const int t = threadIdx.x;
    const int row0 = blockIdx.x * RPB;
    const int bb = row0 >> 12;
    if (flag[0]) lift_body<bf16>(x, lw, lb, h, G0, s0, sH, t, row0, bb);
    else         lift_body<float>(x, lw, lb, h, G0, s0, sH, t, row0, bb);
}

// ---- setup: weff/beff for one layer; 32 blocks = 2 batches x 16 col-stripes ----
template <typename T>
__device__ __forceinline__ void setup_body(
    const float* Gin, const float* sin,
    const void* wq, const void* bq, const void* wb, const void* bbv,
    const void* wk, const void* bk, const void* wv, const void* bv,
    float* weff, float* beff, int layer, int t, int bb, int S,
    float (*gG)[SHP], float (*gK)[SHP], float (*gQ)[SHP],
    float (*tS)[4], float (*mS)[4], float (*wvS)[4],
    float* sS, float* bkS, float* bqS, float* suS, float* bvS)
{
    const int wOff = layer * DD * DD, bOff = layer * DD;
    for (int i = t; i < DD * DD; i += NT) {
        gG[i >> 6][i & 63] = Gin[bb * DD * DD + i];
        gK[i >> 6][i & 63] = Acc<T>::ld(wk, wOff + i);
        gQ[i >> 6][i & 63] = Acc<T>::ld(wq, wOff + i);
    }
    for (int i = t; i < DD * 4; i += NT)
        wvS[i >> 2][i & 3] = Acc<T>::ld(wv, wOff + (i >> 2) * DD + S + (i & 3));
    if (t < DD) {
        sS[t] = sin[bb * DD + t];
        bkS[t] = Acc<T>::ld(bk, bOff + t);
        bqS[t] = Acc<T>::ld(bq, bOff + t);
    }
    if (t < 4) bvS[t] = Acc<T>::ld(bv, bOff + S + t);
    __syncthreads();

    const int r = t >> 2, j = t & 3;
    // P1: T'[:,S] = G.Wv[:,S] + s bv^T   (G symmetric -> row read)
    {
        float a0 = 0.f, a1 = 0.f, a2 = 0.f, a3 = 0.f;
        for (int e = 0; e < DD; e += 4) {
            a0 += gG[r][e]     * wvS[e][j];
            a1 += gG[r][e + 1] * wvS[e + 1][j];
            a2 += gG[r][e + 2] * wvS[e + 2][j];
            a3 += gG[r][e + 3] * wvS[e + 3][j];
        }
        tS[r][j] = (a0 + a1) + (a2 + a3) + sS[r] * bvS[j];
        if (t < 4) {  // su[S+t] = s^T Wv[:,S+t] + N bv
            float u0 = 0.f, u1 = 0.f, u2 = 0.f, u3 = 0.f;
            for (int d = 0; d < DD; d += 4) {
                u0 += sS[d]     * wvS[d][t];
                u1 += sS[d + 1] * wvS[d + 1][t];
                u2 += sS[d + 2] * wvS[d + 2][t];
                u3 += sS[d + 3] * wvS[d + 3][t];
            }
            suS[t] = (u0 + u1) + (u2 + u3) + (float)NN * bvS[t];
        }
    }
    __syncthreads();
    // P2: M[:,S] = Wk^T.T' + bk su^T
    {
        float a0 = 0.f, a1 = 0.f, a2 = 0.f, a3 = 0.f;
        for (int d = 0; d < DD; d += 4) {
            a0 += gK[d][r]     * tS[d][j];
            a1 += gK[d + 1][r] * tS[d + 1][j];
            a2 += gK[d + 2][r] * tS[d + 2][j];
            a3 += gK[d + 3][r] * tS[d + 3][j];
        }
        mS[r][j] = (a0 + a1) + (a2 + a3) + bkS[r] * suS[j];
    }
    __syncthreads();
    // P3: weff[:,S] = Wb[:,S] + C0 * Wq.M[:,S] ; beff[S] = bb[S] + C0 * bq.M[:,S]
    {
        float a0 = 0.f, a1 = 0.f, a2 = 0.f, a3 = 0.f;
        for (int e = 0; e < DD; e += 4) {
            a0 += gQ[r][e]     * mS[e][j];
            a1 += gQ[r][e + 1] * mS[e + 1][j];
            a2 += gQ[r][e + 2] * mS[e + 2][j];
            a3 += gQ[r][e + 3] * mS[e + 3][j];
        }
        weff[bb * DD * DD + r * DD + S + j] =
            Acc<T>::ld(wb, wOff + r * DD + S + j) + C0F * ((a0 + a1) + (a2 + a3));
        if (t < 4) {
            float u = 0.f;
            for (int e = 0; e < DD; e++) u += bqS[e] * mS[e][t];
            beff[bb * DD + S + t] = Acc<T>::ld(bbv, bOff + S + t) + C0F * u;
        }
    }
}

__global__ __launch_bounds__(NT) void setup_kernel(const int* __restrict__ flag,
    const float* __restrict__ Gin, const float* __restrict__ sin,
    const void* __restrict__ wq, const void* __restrict__ bq,
    const void* __restrict__ wb, const void* __restrict__ bbv,
    const void* __restrict__ wk, const void* __restrict__ bk,
    const void* __restrict__ wv, const void* __restrict__ bv,
    float* __restrict__ weff, float* __restrict__ beff, int layer)
{
    __shared__ float gG[DD][SHP], gK[DD][SHP], gQ[DD][SHP];
    __shared__ float tS[DD][4], mS[DD][4], wvS[DD][4];
    __shared__ float sS[DD], bkS[DD], bqS[DD], suS[4], bvS[4];
    const int t = threadIdx.x;
    const int bb = blockIdx.x >> 4;
    const int S = (blockIdx.x & 15) << 2;
    if (flag[0]) setup_body<bf16>(Gin, sin, wq, bq, wb, bbv, wk, bk, wv, bv, weff, beff,
                                  layer, t, bb, S, gG, gK, gQ, tS, mS, wvS, sS, bkS, bqS, suS, bvS);
    else         setup_body<float>(Gin, sin, wq, bq, wb, bbv, wk, bk, wv, bv, weff, beff,
                                  layer, t, bb, S, gG, gK, gQ, tS, mS, wvS, sS, bkS, bqS, suS, bvS);
}

// ---- apply: h' = gelu(h@weff + beff); accumulate next G/s or project ----
template <typename T>
__device__ __forceinline__ void apply_body(
    float* h, const float* weff, const float* beff,
    float* Gout, float* sout, const void* pw, const void* pb, void* out, int is_last,
    float (*wE)[DD], float (*sH)[SHP], float* beS, int t, int row0, int bb)
{
    const int row = t >> 4, c4 = (t & 15) << 2;
    // stage weff (16 KB, flat float4 copy) + h tile + beff
    {
        const float4* wsrc = (const float4*)(weff + (size_t)bb * DD * DD);
        float4* wdst = (float4*)&wE[0][0];
        for (int i = t; i < DD * DD / 4; i += NT) wdst[i] = wsrc[i];
        *(float4*)&sH[row][c4] = *(const float4*)(h + (size_t)(row0 + row) * DD + c4);
        if (t < DD) beS[t] = beff[bb * DD + t];
    }
    __syncthreads();

    float acc[4];
    #pragma unroll
    for (int b = 0; b < 4; b++) acc[b] = beS[c4 + b];
    for (int d = 0; d < DD; d++) {
        float hv = sH[row][d];
        float4 w4 = *(const float4*)&wE[d][c4];
        acc[0] += hv * w4.x; acc[1] += hv * w4.y;
        acc[2] += hv * w4.z; acc[3] += hv * w4.w;
    }
    float o[4];
    #pragma unroll
    for (int b = 0; b < 4; b++) o[b] = gelu_exact(acc[b]);

    if (is_last) {
        float p = 0.f;
        #pragma unroll
        for (int b = 0; b < 4; b++) p += o[b] * Acc<T>::ld(pw, c4 + b);
        p += __shfl_xor(p, 1);
        p += __shfl_xor(p, 2);
        p += __shfl_xor(p, 4);
        p += __shfl_xor(p, 8);
        if ((t & 15) == 0) Acc<T>::st(out, row0 + row, p + Acc<T>::ld(pb, 0));
        return;
    }

    __syncthreads();  // all sH reads complete before overwrite
    float4 o4 = make_float4(o[0], o[1], o[2], o[3]);
    *(float4*)&sH[row][c4] = o4;
    *(float4*)(h + (size_t)(row0 + row) * DD + c4) = o4;
    __syncthreads();
    accG(sH, t, Gout + bb * DD * DD, sout + bb * DD);
}

__global__ __launch_bounds__(NT, 4) void apply_kernel(const int* __restrict__ flag,
    float* __restrict__ h, const float* __restrict__ weff, const float* __restrict__ beff,
    float* __restrict__ Gout, float* __restrict__ sout,
    const void* __restrict__ pw, const void* __restrict__ pb,
    void* __restrict__ out, int is_last)
{
    __shared__ float wE[DD][DD];
    __shared__ float sH[RPB][SHP];
    __shared__ float beS[DD];
    const int t = threadIdx.x;
    const int row0 = blockIdx.x * RPB;
    const int bb = row0 >> 12;
    if (flag[0]) apply_body<bf16>(h, weff, beff, Gout, sout, pw, pb, out, is_last,
                                  wE, sH, beS, t, row0, bb);
    else         apply_body<float>(h, weff, beff, Gout, sout, pw, pb, out, is_last,
                                  wE, sH, beS, t, row0, bb);
}

extern "C" void kernel_launch(void* const* d_in, const int* in_sizes, int n_in,
                              void* d_out, int out_size, void* d_ws, size_t ws_size,
                              hipStream_t stream)
{
    const void* x    = d_in[0];
    const void* lw   = d_in[1];
    const void* lb   = d_in[2];
    const void* blkw = d_in[3];
    const void* blkb = d_in[4];
    const void* qw   = d_in[5];
    const void* qb   = d_in[6];
    const void* kw   = d_in[7];
    const void* kb   = d_in[8];
    const void* vw   = d_in[9];
    const void* vb   = d_in[10];
    const void* pw   = d_in[11];
    const void* pb   = d_in[12];

    float* h    = (float*)d_ws;                       // [2][4096][64]
    float* G    = h + (size_t)NB * NN * DD;           // [4][2][64][64]
    float* s    = G + (size_t)NLAYER * NB * DD * DD;  // [4][2][64]
    float* weff = s + (size_t)NLAYER * NB * DD;       // [2][64][64] (reused per layer)
    float* beff = weff + (size_t)NB * DD * DD;        // [2][64]
    int* flag   = (int*)(beff + (size_t)NB * DD);

    init_kernel<<<1, NT, 0, stream>>>((const unsigned int*)x, G, s, flag);
    lift_kernel<<<NGRID, NT, 0, stream>>>(flag, x, lw, lb, h, G, s);
    for (int i = 0; i < NLAYER; i++) {
        const int last = (i == NLAYER - 1);
        setup_kernel<<<NB * 16, NT, 0, stream>>>(flag, G + i * NB * DD * DD, s + i * NB * DD,
                                                 qw, qb, blkw, blkb, kw, kb, vw, vb,
                                                 weff, beff, i);
        apply_kernel<<<NGRID, NT, 0, stream>>>(flag, h, weff, beff,
                                               last ? nullptr : (G + (i + 1) * NB * DD * DD),
                                               last ? nullptr : (s + (i + 1) * NB * DD),
                                               pw, pb, d_out, last);
    }
}

// Round 5
// 423.594 us; speedup vs baseline: 1.5107x; 1.5107x over previous
//
#include <hip/hip_runtime.h>
#include <hip/hip_bf16.h>
#include <math.h>

// GNO collapsed: h = lift(x); per layer h = gelu(h@weff + beff) where
//   weff = Wb + c0*Wq@M, beff = bb + c0*bq@M,
//   M = Wk^T G Wv + (Wk^T s) bv^T + bk (s^T Wv) + N bk bv^T, G = h^T h, s = h^T 1.
// Round 5: NO global atomics (round 4's 2M contended atomicAdds each cost a
// 64B line RMW round-trip -> 300 MB/dispatch). Blocks write private G/s
// partials; a split-K reduce kernel sums them. 14 tiny dispatches.

#define NLAYER 4
#define NB 2
#define NN 4096
#define DD 64
#define RPB 16
#define NT 256
#define NGRID ((NB*NN)/RPB)   // 512 blocks
#define PPB (NGRID/NB)        // 256 partial slots per batch
#define C0F (1.0f/32768.0f)   // (1/sqrt(64))/4096
#define SHP 68                // padded LDS stride

typedef __hip_bfloat16 bf16;

__device__ __forceinline__ float b2f(const bf16 v) { return __bfloat162float(v); }

template <typename T> struct Acc;
template <> struct Acc<float> {
    static __device__ __forceinline__ float ld(const void* p, int i) { return ((const float*)p)[i]; }
    static __device__ __forceinline__ void st(void* p, int i, float v) { ((float*)p)[i] = v; }
};
template <> struct Acc<bf16> {
    static __device__ __forceinline__ float ld(const void* p, int i) { return b2f(((const bf16*)p)[i]); }
    static __device__ __forceinline__ void st(void* p, int i, float v) { ((bf16*)p)[i] = __float2bfloat16(v); }
};

__device__ __forceinline__ float gelu_exact(float x) {
    return 0.5f * x * (1.0f + erff(x * 0.70710678118654752f));
}

// Per-block G/s partial: 4x4 tile/thread over RPB rows, plain stores (no atomics).
__device__ __forceinline__ void accG_part(const float (*sH)[SHP], int t,
                                          float* __restrict__ Gp, float* __restrict__ sp)
{
    const int tr4 = (t >> 4) << 2, tc4 = (t & 15) << 2;
    float m[4][4];
    #pragma unroll
    for (int a = 0; a < 4; a++)
        #pragma unroll
        for (int b = 0; b < 4; b++) m[a][b] = 0.f;
    #pragma unroll
    for (int n = 0; n < RPB; n++) {
        float4 he = *(const float4*)&sH[n][tr4];
        float4 hc = *(const float4*)&sH[n][tc4];
        float ha[4] = {he.x, he.y, he.z, he.w};
        float ca[4] = {hc.x, hc.y, hc.z, hc.w};
        #pragma unroll
        for (int a = 0; a < 4; a++)
            #pragma unroll
            for (int b = 0; b < 4; b++) m[a][b] += ha[a] * ca[b];
    }
    #pragma unroll
    for (int a = 0; a < 4; a++)
        *(float4*)&Gp[(tr4 + a) * DD + tc4] = make_float4(m[a][0], m[a][1], m[a][2], m[a][3]);
    if (t < DD) {
        float ss = 0.f;
        #pragma unroll
        for (int n = 0; n < RPB; n++) ss += sH[n][t];
        sp[t] = ss;
    }
}

// ---- init: classify input dtype only (1 = bf16, 0 = fp32) ----
__global__ __launch_bounds__(NT) void init_kernel(const unsigned int* __restrict__ x,
                                                  int* __restrict__ flag)
{
    __shared__ int tot;
    const int t = threadIdx.x;
    if (t == 0) tot = 0;
    __syncthreads();
    int cnt = 0;
    for (int i = t; i < 8192; i += NT) {
        unsigned u = x[i] & 0xFFFFu;
        int e = (u >> 7) & 0xFF;
        cnt += (u == 0u || (e >= 100 && e <= 142)) ? 1 : 0;
    }
    atomicAdd(&tot, cnt);
    __syncthreads();
    if (t == 0) flag[0] = (tot > 4915) ? 1 : 0;
}

// ---- lift: h = x @ lw + lb; write G/s partial ----
template <typename T>
__device__ __forceinline__ void lift_body(const void* x, const void* lw, const void* lb,
                                          float* h, float* Gp, float* sp,
                                          float (*sH)[SHP], int t, int row0)
{
    const int row = t >> 4, c4 = (t & 15) << 2;
    const int gr = row0 + row;
    float x0 = Acc<T>::ld(x, gr * 3 + 0);
    float x1 = Acc<T>::ld(x, gr * 3 + 1);
    float x2 = Acc<T>::ld(x, gr * 3 + 2);
    float o[4];
    #pragma unroll
    for (int b = 0; b < 4; b++) {
        int c = c4 + b;
        o[b] = Acc<T>::ld(lb, c) + x0 * Acc<T>::ld(lw, c)
             + x1 * Acc<T>::ld(lw, DD + c) + x2 * Acc<T>::ld(lw, 2 * DD + c);
    }
    float4 o4 = make_float4(o[0], o[1], o[2], o[3]);
    *(float4*)&sH[row][c4] = o4;
    *(float4*)(h + (size_t)gr * DD + c4) = o4;
    __syncthreads();
    accG_part(sH, t, Gp, sp);
}

__global__ __launch_bounds__(NT, 4) void lift_kernel(const int* __restrict__ flag,
    const void* __restrict__ x, const void* __restrict__ lw, const void* __restrict__ lb,
    float* __restrict__ h, float* __restrict__ Gpart, float* __restrict__ spart)
{
    __shared__ float sH[RPB][SHP];
    const int t = threadIdx.x;
    const int row0 = blockIdx.x * RPB;
    float* Gp = Gpart + (size_t)blockIdx.x * DD * DD;
    float* sp = spart + (size_t)blockIdx.x * DD;
    if (flag[0]) lift_body<bf16>(x, lw, lb, h, Gp, sp, sH, t, row0);
    else         lift_body<float>(x, lw, lb, h, Gp, sp, sH, t, row0);
}

// ---- reduce: G[b] = sum_k Gpart[b*PPB+k], s[b] = sum_k spart. Split-K 4x64. ----
__global__ __launch_bounds__(NT) void reduce_kernel(
    const float* __restrict__ Gpart, const float* __restrict__ spart,
    float* __restrict__ G, float* __restrict__ s)
{
    __shared__ float red[4][DD];
    const int g = blockIdx.x, t = threadIdx.x;
    const int lane = t & 63, kp = t >> 6;     // kp in 0..3
    if (g < 2 * DD) {                          // 128 G-blocks: one h-row of G each
        const int batch = g >> 6;
        const int cell = (g & 63) * DD + lane;
        const float* src = Gpart + (size_t)(batch * PPB + kp * 64) * (DD * DD) + cell;
        float acc = 0.f;
        #pragma unroll 8
        for (int k = 0; k < 64; k++) acc += src[(size_t)k * DD * DD];
        red[kp][lane] = acc;
        __syncthreads();
        if (t < DD) G[batch * DD * DD + (g & 63) * DD + t]
                        = (red[0][t] + red[1][t]) + (red[2][t] + red[3][t]);
    } else {                                   // 2 s-blocks
        const int batch = g - 2 * DD;
        const float* src = spart + (size_t)(batch * PPB + kp * 64) * DD + lane;
        float acc = 0.f;
        #pragma unroll 8
        for (int k = 0; k < 64; k++) acc += src[(size_t)k * DD];
        red[kp][lane] = acc;
        __syncthreads();
        if (t < DD) s[batch * DD + t] = (red[0][t] + red[1][t]) + (red[2][t] + red[3][t]);
    }
}

// ---- setup: weff/beff for one layer; 32 blocks = 2 batches x 16 col-stripes ----
template <typename T>
__device__ __forceinline__ void setup_body(
    const float* Gin, const float* sin,
    const void* wq, const void* bq, const void* wb, const void* bbv,
    const void* wk, const void* bk, const void* wv, const void* bv,
    float* weff, float* beff, int layer, int t, int bb, int S,
    float (*gG)[SHP], float (*gK)[SHP], float (*gQ)[SHP],
    float (*tS)[4], float (*mS)[4], float (*wvS)[4],
    float* sS, float* bkS, float* bqS, float* suS, float* bvS)
{
    const int wOff = layer * DD * DD, bOff = layer * DD;
    for (int i = t; i < DD * DD; i += NT) {
        gG[i >> 6][i & 63] = Gin[bb * DD * DD + i];
        gK[i >> 6][i & 63] = Acc<T>::ld(wk, wOff + i);
        gQ[i >> 6][i & 63] = Acc<T>::ld(wq, wOff + i);
    }
    for (int i = t; i < DD * 4; i += NT)
        wvS[i >> 2][i & 3] = Acc<T>::ld(wv, wOff + (i >> 2) * DD + S + (i & 3));
    if (t < DD) {
        sS[t] = sin[bb * DD + t];
        bkS[t] = Acc<T>::ld(bk, bOff + t);
        bqS[t] = Acc<T>::ld(bq, bOff + t);
    }
    if (t < 4) bvS[t] = Acc<T>::ld(bv, bOff + S + t);
    __syncthreads();

    const int r = t >> 2, j = t & 3;
    // P1: T'[:,S] = G.Wv[:,S] + s bv^T  (G symmetric -> row read)
    {
        float a0 = 0.f, a1 = 0.f, a2 = 0.f, a3 = 0.f;
        for (int e = 0; e < DD; e += 4) {
            a0 += gG[r][e]     * wvS[e][j];
            a1 += gG[r][e + 1] * wvS[e + 1][j];
            a2 += gG[r][e + 2] * wvS[e + 2][j];
            a3 += gG[r][e + 3] * wvS[e + 3][j];
        }
        tS[r][j] = (a0 + a1) + (a2 + a3) + sS[r] * bvS[j];
        if (t < 4) {
            float u0 = 0.f, u1 = 0.f, u2 = 0.f, u3 = 0.f;
            for (int d = 0; d < DD; d += 4) {
                u0 += sS[d]     * wvS[d][t];
                u1 += sS[d + 1] * wvS[d + 1][t];
                u2 += sS[d + 2] * wvS[d + 2][t];
                u3 += sS[d + 3] * wvS[d + 3][t];
            }
            suS[t] = (u0 + u1) + (u2 + u3) + (float)NN * bvS[t];
        }
    }
    __syncthreads();
    // P2: M[:,S] = Wk^T.T' + bk su^T
    {
        float a0 = 0.f, a1 = 0.f, a2 = 0.f, a3 = 0.f;
        for (int d = 0; d < DD; d += 4) {
            a0 += gK[d][r]     * tS[d][j];
            a1 += gK[d + 1][r] * tS[d + 1][j];
            a2 += gK[d + 2][r] * tS[d + 2][j];
            a3 += gK[d + 3][r] * tS[d + 3][j];
        }
        mS[r][j] = (a0 + a1) + (a2 + a3) + bkS[r] * suS[j];
    }
    __syncthreads();
    // P3: weff[:,S] = Wb[:,S] + C0*Wq.M[:,S]; beff[S] = bb[S] + C0*bq.M[:,S]
    {
        float a0 = 0.f, a1 = 0.f, a2 = 0.f, a3 = 0.f;
        for (int e = 0; e < DD; e += 4) {
            a0 += gQ[r][e]     * mS[e][j];
            a1 += gQ[r][e + 1] * mS[e + 1][j];
            a2 += gQ[r][e + 2] * mS[e + 2][j];
            a3 += gQ[r][e + 3] * mS[e + 3][j];
        }
        weff[bb * DD * DD + r * DD + S + j] =
            Acc<T>::ld(wb, wOff + r * DD + S + j) + C0F * ((a0 + a1) + (a2 + a3));
        if (t < 4) {
            float u = 0.f;
            for (int e = 0; e < DD; e++) u += bqS[e] * mS[e][t];
            beff[bb * DD + S + t] = Acc<T>::ld(bbv, bOff + S + t) + C0F * u;
        }
    }
}

__global__ __launch_bounds__(NT) void setup_kernel(const int* __restrict__ flag,
    const float* __restrict__ Gin, const float* __restrict__ sin,
    const void* __restrict__ wq, const void* __restrict__ bq,
    const void* __restrict__ wb, const void* __restrict__ bbv,
    const void* __restrict__ wk, const void* __restrict__ bk,
    const void* __restrict__ wv, const void* __restrict__ bv,
    float* __restrict__ weff, float* __restrict__ beff, int layer)
{
    __shared__ float gG[DD][SHP], gK[DD][SHP], gQ[DD][SHP];
    __shared__ float tS[DD][4], mS[DD][4], wvS[DD][4];
    __shared__ float sS[DD], bkS[DD], bqS[DD], suS[4], bvS[4];
    const int t = threadIdx.x;
    const int bb = blockIdx.x >> 4;
    const int S = (blockIdx.x & 15) << 2;
    if (flag[0]) setup_body<bf16>(Gin, sin, wq, bq, wb, bbv, wk, bk, wv, bv, weff, beff,
                                  layer, t, bb, S, gG, gK, gQ, tS, mS, wvS, sS, bkS, bqS, suS, bvS);
    else         setup_body<float>(Gin, sin, wq, bq, wb, bbv, wk, bk, wv, bv, weff, beff,
                                  layer, t, bb, S, gG, gK, gQ, tS, mS, wvS, sS, bkS, bqS, suS, bvS);
}

// ---- apply: h' = gelu(h@weff + beff); write next G/s partials or project ----
template <typename T>
__device__ __forceinline__ void apply_body(
    float* h, const float* weff, const float* beff,
    float* Gp, float* sp, const void* pw, const void* pb, void* out, int is_last,
    float (*wE)[DD], float (*sH)[SHP], float* beS, int t, int row0, int bb)
{
    const int row = t >> 4, c4 = (t & 15) << 2;
    {
        const float4* wsrc = (const float4*)(weff + (size_t)bb * DD * DD);
        float4* wdst = (float4*)&wE[0][0];
        for (int i = t; i < DD * DD / 4; i += NT) wdst[i] = wsrc[i];
        *(float4*)&sH[row][c4] = *(const float4*)(h + (size_t)(row0 + row) * DD + c4);
        if (t < DD) beS[t] = beff[bb * DD + t];
    }
    __syncthreads();

    float acc[4];
    #pragma unroll
    for (int b = 0; b < 4; b++) acc[b] = beS[c4 + b];
    for (int d = 0; d < DD; d++) {
        float hv = sH[row][d];
        float4 w4 = *(const float4*)&wE[d][c4];
        acc[0] += hv * w4.x; acc[1] += hv * w4.y;
        acc[2] += hv * w4.z; acc[3] += hv * w4.w;
    }
    float o[4];
    #pragma unroll
    for (int b = 0; b < 4; b++) o[b] = gelu_exact(acc[b]);

    if (is_last) {
        float p = 0.f;
        #pragma unroll
        for (int b = 0; b < 4; b++) p += o[b] * Acc<T>::ld(pw, c4 + b);
        p += __shfl_xor(p, 1);
        p += __shfl_xor(p, 2);
        p += __shfl_xor(p, 4);
        p += __shfl_xor(p, 8);
        if ((t & 15) == 0) Acc<T>::st(out, row0 + row, p + Acc<T>::ld(pb, 0));
        return;
    }

    __syncthreads();
    float4 o4 = make_float4(o[0], o[1], o[2], o[3]);
    *(float4*)&sH[row][c4] = o4;
    *(float4*)(h + (size_t)(row0 + row) * DD + c4) = o4;
    __syncthreads();
    accG_part(sH, t, Gp, sp);
}

__global__ __launch_bounds__(NT, 4) void apply_kernel(const int* __restrict__ flag,
    float* __restrict__ h, const float* __restrict__ weff, const float* __restrict__ beff,
    float* __restrict__ Gpart, float* __restrict__ spart,
    const void* __restrict__ pw, const void* __restrict__ pb,
    void* __restrict__ out, int is_last)
{
    __shared__ float wE[DD][DD];
    __shared__ float sH[RPB][SHP];
    __shared__ float beS[DD];
    const int t = threadIdx.x;
    const int row0 = blockIdx.x * RPB;
    const int bb = row0 >> 12;
    float* Gp = Gpart + (size_t)blockIdx.x * DD * DD;
    float* sp = spart + (size_t)blockIdx.x * DD;
    if (flag[0]) apply_body<bf16>(h, weff, beff, Gp, sp, pw, pb, out, is_last,
                                  wE, sH, beS, t, row0, bb);
    else         apply_body<float>(h, weff, beff, Gp, sp, pw, pb, out, is_last,
                                   wE, sH, beS, t, row0, bb);
}

extern "C" void kernel_launch(void* const* d_in, const int* in_sizes, int n_in,
                              void* d_out, int out_size, void* d_ws, size_t ws_size,
                              hipStream_t stream)
{
    const void* x    = d_in[0];
    const void* lw   = d_in[1];
    const void* lb   = d_in[2];
    const void* blkw = d_in[3];
    const void* blkb = d_in[4];
    const void* qw   = d_in[5];
    const void* qb   = d_in[6];
    const void* kw   = d_in[7];
    const void* kb   = d_in[8];
    const void* vw   = d_in[9];
    const void* vb   = d_in[10];
    const void* pw   = d_in[11];
    const void* pb   = d_in[12];

    float* h     = (float*)d_ws;                         // [2][4096][64]   2 MB
    float* Gpart = h + (size_t)NB * NN * DD;             // [512][64][64]   8 MB
    float* spart = Gpart + (size_t)NGRID * DD * DD;      // [512][64]     128 KB
    float* G     = spart + (size_t)NGRID * DD;           // [2][64][64]
    float* s     = G + (size_t)NB * DD * DD;             // [2][64]
    float* weff  = s + (size_t)NB * DD;                  // [2][64][64]
    float* beff  = weff + (size_t)NB * DD * DD;          // [2][64]
    int* flag    = (int*)(beff + (size_t)NB * DD);

    init_kernel<<<1, NT, 0, stream>>>((const unsigned int*)x, flag);
    lift_kernel<<<NGRID, NT, 0, stream>>>(flag, x, lw, lb, h, Gpart, spart);
    for (int i = 0; i < NLAYER; i++) {
        const int last = (i == NLAYER - 1);
        reduce_kernel<<<2 * DD + NB, NT, 0, stream>>>(Gpart, spart, G, s);
        setup_kernel<<<NB * 16, NT, 0, stream>>>(flag, G, s,
                                                 qw, qb, blkw, blkb, kw, kb, vw, vb,
                                                 weff, beff, i);
        apply_kernel<<<NGRID, NT, 0, stream>>>(flag, h, weff, beff, Gpart, spart,
                                               pw, pb, d_out, last);
    }
}